// Round 7
// baseline (828.935 us; speedup 1.0000x reference)
//
#include <hip/hip_runtime.h>
#include <math.h>

// RadialProfileLoss — chunk-relative windowed-Gaussian radial histogram.
// sigma = bw/2 => W[p][b] = exp(-2*(u-(b+0.5))^2), u = r/bw, bw = 127/64.
// Structure: 4-row chunks; window base kb = min(floor(u))-3 constant per
// chunk; weights computed in chunk frame T = u-f_min+2.5 in [2.5,5.02) over
// S=9 STATIC slots (w_min = exp(-2*5.02^2) ~ 1.6e-22, still normal fp32;
// 8-row chunks would underflow). Kills R4's per-row divergent shift/flush
// (~2900 cyc/row, VALUBusy 20%) and batches 16 coalesced loads per chunk.
// Guard-padded LDS hist absorbs out-of-range bins without bounds checks.
// Chunks are 4-aligned so the center (127.5, boundary y=128) never falls
// inside a chunk -> r monotone per chunk -> min floor at an endpoint.

#define NBINS 64
#define S     9          // chunk window slots
#define G     2          // images per block
#define NIMG  384        // 32*12
#define HDIM  256
#define WDIM  256
#define BANDS 16
#define BANDROWS 16      // HDIM / BANDS
#define CHUNK 4
#define NCHUNK (BANDROWS / CHUNK)
#define GUARD 4          // kb >= -3 -> padded index >= 1
#define HSLOTS 80        // 63+GUARD+S-1 = 75 max -> 80

#define LOG2E 1.4426950408889634f
#define EXP_M4 0.018315638888734179f   // e^-4

__device__ __forceinline__ float fexp2(float x) {
#if __has_builtin(__builtin_amdgcn_exp2f)
  return __builtin_amdgcn_exp2f(x);
#else
  return exp2f(x);
#endif
}

// ---------------------------------------------------------------------------
// Main profile kernel. thread = column x; walks 16 rows as 4 chunks of 4.
// ---------------------------------------------------------------------------
__global__ __launch_bounds__(256) void radial_prof_kernel(
    const float* __restrict__ pred,
    const float* __restrict__ targ,
    float* __restrict__ prof)          // [NIMG][2][NBINS]
{
  const int x    = threadIdx.x;               // column 0..255
  const int band = blockIdx.x & (BANDS - 1);  // 0..15
  const int gi   = blockIdx.x >> 4;           // 0..191
  const int g0   = gi * G;

  __shared__ float hist[G][2][HSLOTS];
  for (int i = threadIdx.x; i < G * 2 * HSLOTS; i += 256) ((float*)hist)[i] = 0.f;
  __syncthreads();

  const float dx     = (float)x - 127.5f;
  const int   y0     = band * BANDROWS;
  const float inv_bw = 64.0f / 127.0f;

  float dy  = (float)y0 - 127.5f;
  float rsq = dx * dx + dy * dy;       // exact fp32 (half-integer grid)

  const size_t istr = (size_t)HDIM * WDIM;
  const float* pbase = pred + (size_t)g0 * istr + (size_t)y0 * WDIM + x;
  const float* tbase = targ + (size_t)g0 * istr + (size_t)y0 * WDIM + x;

  for (int c = 0; c < NCHUNK; ++c) {
    // ---- geometry for the chunk's 4 rows (no memory deps) ----
    float u[CHUNK];
    #pragma unroll
    for (int r = 0; r < CHUNK; ++r) {
      u[r] = sqrtf(rsq) * inv_bw;
      rsq += 2.0f * dy + 1.0f;         // exact
      dy  += 1.0f;
    }
    // r monotone within a 4-aligned chunk -> min floor at an endpoint
    const float fm = fminf(floorf(u[0]), floorf(u[CHUNK - 1]));
    const int   kb = (int)fm - 3;      // bin of slot 0, in [-3, 87]

    if (kb < NBINS) {                  // skip chunks fully past bin 63
      // ---- batched loads: 16 coalesced wave-loads in flight ----
      float dp0[CHUNK], dp1[CHUNK], dt0[CHUNK], dt1[CHUNK];
      #pragma unroll
      for (int r = 0; r < CHUNK; ++r) {
        dp0[r] = pbase[r * WDIM];
        dp1[r] = pbase[r * WDIM + istr];
        dt0[r] = tbase[r * WDIM];
        dt1[r] = tbase[r * WDIM + istr];
      }

      float acc[G][2][S];
      #pragma unroll
      for (int g = 0; g < G; ++g)
        #pragma unroll
        for (int t = 0; t < 2; ++t)
          #pragma unroll
          for (int j = 0; j < S; ++j) acc[g][t][j] = 0.f;

      // ---- accumulate: weights in chunk frame, static slot indices ----
      #pragma unroll
      for (int r = 0; r < CHUNK; ++r) {
        const float T = (u[r] - fm) + 2.5f;     // [2.5, 5.02)
        float w = fexp2(-(2.0f * LOG2E) * T * T);       // >= 1.6e-22, normal
        float m = fexp2((4.0f * T - 2.0f) * LOG2E);
        #pragma unroll
        for (int j = 0; j < S; ++j) {
          acc[0][0][j] = fmaf(w, dp0[r], acc[0][0][j]);
          acc[0][1][j] = fmaf(w, dt0[r], acc[0][1][j]);
          acc[1][0][j] = fmaf(w, dp1[r], acc[1][0][j]);
          acc[1][1][j] = fmaf(w, dt1[r], acc[1][1][j]);
          w *= m;
          m *= EXP_M4;
        }
      }

      // ---- one flush per chunk (guard pad -> no bounds checks) ----
      #pragma unroll
      for (int j = 0; j < S; ++j) {
        const int bp = kb + GUARD + j;          // [1, 75]
        atomicAdd(&hist[0][0][bp], acc[0][0][j]);
        atomicAdd(&hist[0][1][bp], acc[0][1][j]);
        atomicAdd(&hist[1][0][bp], acc[1][0][j]);
        atomicAdd(&hist[1][1][bp], acc[1][1][j]);
      }
    }
    pbase += CHUNK * WDIM;
    tbase += CHUNK * WDIM;
  }
  __syncthreads();

  // hist[g][t][GUARD..GUARD+63] -> prof; one element per thread
  {
    const int i = threadIdx.x;
    const int g = i >> 7, t = (i >> 6) & 1, b = i & 63;
    atomicAdd(&prof[((size_t)(g0 + g) * 2 + t) * NBINS + b], hist[g][t][b + GUARD]);
  }
}

// ---------------------------------------------------------------------------
// den[b] = sum_p W[p][b] — same chunk math, weights only. 64 blocks x 4 rows.
// ---------------------------------------------------------------------------
__global__ __launch_bounds__(256) void den_kernel(float* __restrict__ den)
{
  const int x  = threadIdx.x;
  const int y0 = blockIdx.x * CHUNK;   // 0..252

  __shared__ float hist[HSLOTS];
  if (threadIdx.x < HSLOTS) hist[threadIdx.x] = 0.f;
  __syncthreads();

  const float dx     = (float)x - 127.5f;
  const float inv_bw = 64.0f / 127.0f;
  float dy  = (float)y0 - 127.5f;
  float rsq = dx * dx + dy * dy;

  float u[CHUNK];
  #pragma unroll
  for (int r = 0; r < CHUNK; ++r) {
    u[r] = sqrtf(rsq) * inv_bw;
    rsq += 2.0f * dy + 1.0f;
    dy  += 1.0f;
  }
  const float fm = fminf(floorf(u[0]), floorf(u[CHUNK - 1]));
  const int   kb = (int)fm - 3;

  if (kb < NBINS) {
    float acc[S];
    #pragma unroll
    for (int j = 0; j < S; ++j) acc[j] = 0.f;
    #pragma unroll
    for (int r = 0; r < CHUNK; ++r) {
      const float T = (u[r] - fm) + 2.5f;
      float w = fexp2(-(2.0f * LOG2E) * T * T);
      float m = fexp2((4.0f * T - 2.0f) * LOG2E);
      #pragma unroll
      for (int j = 0; j < S; ++j) {
        acc[j] += w;
        w *= m;
        m *= EXP_M4;
      }
    }
    #pragma unroll
    for (int j = 0; j < S; ++j) atomicAdd(&hist[kb + GUARD + j], acc[j]);
  }
  __syncthreads();
  if (threadIdx.x < NBINS) atomicAdd(&den[threadIdx.x], hist[threadIdx.x + GUARD]);
}

// ---------------------------------------------------------------------------
// Loss: one WAVE per image, lane-coalesced loads (lane = bin), shuffle
// reductions. Replaces the single-block version (512B-strided lane loads,
// one CU, latency-serial — the ~150us bench-vs-kernel gap in R1-R4).
// ---------------------------------------------------------------------------
__global__ __launch_bounds__(256) void loss_kernel(
    const float* __restrict__ prof,
    const float* __restrict__ den,
    float* __restrict__ out)
{
  const int wid  = threadIdx.x >> 6;           // wave 0..3
  const int lane = threadIdx.x & 63;           // = bin
  const int img  = blockIdx.x * 4 + wid;       // 0..383

  const float inv_d = 1.0f / fmaxf(den[lane], 1e-8f);
  const float* base = prof + (size_t)img * 2 * NBINS;
  const float P = base[lane] * inv_d;
  const float T = base[NBINS + lane] * inv_d;

  float s = T;
  #pragma unroll
  for (int off = 32; off > 0; off >>= 1) s += __shfl_xor(s, off);
  const float ybar = s * (1.0f / NBINS);

  const float wb = ((float)lane + 0.5f) * (1.0f / 32.0f);  // centers/mean(centers)
  const float d1 = P - T;
  const float d2 = T - ybar;
  float sse = wb * d1 * d1;
  float ssy = wb * d2 * d2;
  #pragma unroll
  for (int off = 32; off > 0; off >>= 1) sse += __shfl_xor(sse, off);
  #pragma unroll
  for (int off = 32; off > 0; off >>= 1) ssy += __shfl_xor(ssy, off);

  if (lane == 0)
    atomicAdd(out, (sse / fmaxf(ssy, 1e-8f)) * (1.0f / NIMG));
}

// ---------------------------------------------------------------------------
extern "C" void kernel_launch(void* const* d_in, const int* in_sizes, int n_in,
                              void* d_out, int out_size, void* d_ws, size_t ws_size,
                              hipStream_t stream) {
  const float* pred = (const float*)d_in[0];
  const float* targ = (const float*)d_in[1];

  float* prof = (float*)d_ws;                       // NIMG*2*NBINS floats
  float* den  = prof + (size_t)NIMG * 2 * NBINS;    // NBINS floats

  hipMemsetAsync(d_ws, 0, ((size_t)NIMG * 2 * NBINS + NBINS) * sizeof(float), stream);
  hipMemsetAsync(d_out, 0, sizeof(float), stream);  // loss accumulates atomically

  den_kernel<<<HDIM / CHUNK, 256, 0, stream>>>(den);
  radial_prof_kernel<<<(NIMG / G) * BANDS, 256, 0, stream>>>(pred, targ, prof);
  loss_kernel<<<NIMG / 4, 256, 0, stream>>>(prof, den, (float*)d_out);
}